// Round 4
// baseline (9114.220 us; speedup 1.0000x reference)
//
#include <hip/hip_runtime.h>
#include <hip/hip_bf16.h>
#include <cstdint>
#include <cstddef>

#define DEV __device__ __forceinline__

typedef _Float16 h2v __attribute__((ext_vector_type(2)));
typedef unsigned u4v __attribute__((ext_vector_type(4)));

DEV float sigmoidf_(float x) { return 1.0f / (1.0f + __expf(-x)); }
DEV float tanhf_(float x) {
    float e = __expf(2.0f * x);
    return 1.0f - 2.0f / (e + 1.0f);
}
DEV h2v asH2(unsigned x) { union { unsigned u; h2v h; } c; c.u = x; return c.h; }

// Un-sinkable, un-rematerializable 16B load (resident weights).
DEV u4v gload(const void* p) {
    u4v r;
    asm volatile("global_load_dwordx4 %0, %1, off\n\ts_waitcnt vmcnt(0)"
                 : "=v"(r) : "v"(p) : "memory");
    return r;
}

// LDS-only barrier: does NOT drain vmcnt; global prefetch/stores stay in flight.
#define LDS_BARRIER() asm volatile("s_waitcnt lgkmcnt(0)\n\ts_barrier" ::: "memory")

// ---------------------------------------------------------------------------
// Pack 10 matrices (256x64 each) to f16 pairs, split-K layout:
//   dst[m][half][qs][u][w]   (qs = q*4+s: gate q, slice s; w = word 0..3)
// m: 0-2 l1Whh, 3-5 l2Whh, 6-7 Wih12 (l1 layers 1,2), 8-9 l2Wih layers 1,2.
// Quad (half,q,s,u) holds W[gate q][unit u][k = 32*half + 8*s .. +7].
// ---------------------------------------------------------------------------
__global__ __launch_bounds__(256) void pack_w(
    const float* __restrict__ l1Whh, const float* __restrict__ l2Whh,
    const float* __restrict__ Wih12, const float* __restrict__ l2Wih,
    unsigned* __restrict__ wP)
{
    int idx = blockIdx.x * 256 + threadIdx.x;   // 10*8192 = 81920
    int m = idx >> 13;
    int rem = idx & 8191;
    int half = rem >> 12;
    int qs = (rem >> 8) & 15;
    int u = (rem >> 2) & 63;
    int w = rem & 3;
    int q = qs >> 2, s = qs & 3;
    int jp = 16 * half + 4 * s + w;

    const float* W;
    if (m < 3)      W = l1Whh + (size_t)m * 16384;
    else if (m < 6) W = l2Whh + (size_t)(m - 3) * 16384;
    else if (m < 8) W = Wih12 + (size_t)(m - 6) * 16384;
    else            W = l2Wih + (size_t)(m - 7) * 16384;   // layers 1,2

    const float* row = W + (size_t)(q * 64 + u) * 64;
    union { h2v h; unsigned u32; } c;
    c.h = (h2v){(_Float16)row[2 * jp], (_Float16)row[2 * jp + 1]};
    wP[idx] = c.u32;
}

// ---------------------------------------------------------------------------
// Input projection (layer 0 of each stack only): xg[b,t,u*4+q] unit-major.
// ---------------------------------------------------------------------------
__global__ __launch_bounds__(256) void proj_kernel(
    const float* __restrict__ x, const float* __restrict__ Wih,
    const float* __restrict__ bias, const float* __restrict__ gate,
    float* __restrict__ xg, int D, int T)
{
    __shared__ float xS[16 * 64];
    int tb = T / 16;
    int b  = blockIdx.x / tb;
    int t0 = (blockIdx.x % tb) * 16;
    int tid = threadIdx.x;

    int n = 16 * D;
    for (int e = tid; e < n; e += 256) {
        int t = e / D;
        int i = e - t * D;
        float v = x[((size_t)(b * T + t0 + t)) * D + i];
        if (gate) v += gate[b * T + t0 + t];
        xS[t * D + i] = v;
    }
    __syncthreads();

    int g = tid;
    float acc[16];
    float bg = bias[g];
#pragma unroll
    for (int t = 0; t < 16; t++) acc[t] = bg;

    const float* wr = Wih + (size_t)g * D;
    for (int i = 0; i < D; i++) {
        float w = wr[i];
#pragma unroll
        for (int t = 0; t < 16; t++) acc[t] += xS[t * D + i] * w;
    }

    float* og = xg + ((size_t)(b * T + t0)) * 256 + (g & 63) * 4 + (g >> 6);
#pragma unroll
    for (int t = 0; t < 16; t++) og[(size_t)t * 256] = acc[t];
}

// ---------------------------------------------------------------------------
// Chunked 3-layer LSTM scan v19: ONE block per batch, THREE waves (1/layer).
//
// v15-v18 post-mortem: 4 different structures all ~2300 cy/tick; v18's heavy
// wave = 9.2 cy/fdot2 with only 4 independent 32-deep accumulate chains ->
// DEPENDENT-CHAIN LATENCY bound, not issue/sync/LDS-BW bound. v19:
//  * SCANTICK: 16 partial accumulators (4/gate, round-robin over h-quads);
//    chains 32->8 deep, ILP 4->16; tree-combine at the end.
//  * h-quads pre-read into registers (HQ_RELOAD) right after the h write
//    (same-wave DS in-order => correct); the ~120cy read latency is then
//    covered by interleaved independent work instead of stalling.
//  * Half-1 chunk-GEMM (Wih.h_below, ticks 4-7) interleaved between
//    SCANTICKs 0-3 into separate acc4b regs -> fills the h-latency shadow.
//  * Everything else = v18: resident Whh (128 VGPR), Wih in LDS read once
//    per 4 ticks, epochs of RR=8 ticks, 1 barrier/epoch, hchunk parity
//    double-buffer, acc4a doubles as L0's rolling x-prefetch.
// ---------------------------------------------------------------------------
#define RR 8

__global__
__attribute__((amdgpu_flat_work_group_size(192, 192), amdgpu_waves_per_eu(1, 1)))
void scan3_kernel(
    const float* __restrict__ xg, const unsigned* __restrict__ whhP,
    const unsigned* __restrict__ wihP, const float* __restrict__ bvec,
    const float* __restrict__ h0, const float* __restrict__ c0,
    float* __restrict__ Hout, int T)
{
    __shared__ __align__(16) u4v wihS[4096];                 // 64 KB (Wih l1,l2)
    __shared__ __align__(16) _Float16 hchunk[2][2][RR][64];  // 4 KB
    __shared__ __align__(16) _Float16 hself[3][64];

    const int b = blockIdx.x, tid = threadIdx.x;
    const int l = tid >> 6, u = tid & 63;

    // stage Wih (both layers, packed layout) into LDS
    for (int i = tid; i < 4096; i += 192) wihS[i] = ((const u4v*)wihP)[i];

    // resident Whh: whh[g*8+ks] = W[gate g][unit u][k=8*ks..8*ks+7]
    u4v whh[32];
    {
        const u4v* wp = (const u4v*)whhP + (size_t)l * 2048 + u;
#pragma unroll
        for (int g = 0; g < 4; g++)
#pragma unroll
            for (int ks = 0; ks < 8; ks++)
                whh[g * 8 + ks] = gload(wp + (ks >> 2) * 1024 + (g * 4 + (ks & 3)) * 64);
    }

    float cst = c0[l * 128 + b * 64 + u];
    hself[l][u] = (_Float16)h0[l * 128 + b * 64 + u];
    float4 bl = make_float4(0.f, 0.f, 0.f, 0.f);
    if (l > 0) {
        const float* bb = bvec + l * 256;
        bl = make_float4(bb[u], bb[64 + u], bb[128 + u], bb[192 + u]);
    }

    // acc4a: L0 = rolling x prefetch; L1/L2 = half-0 GEMM accums.
    // acc4b: L1/L2 = half-1 GEMM accums (separate regs: half-1 GEMM is
    // interleaved with ticks 0-3 which still consume acc4a).
    const float4* xp = (const float4*)(xg + (size_t)b * T * 256) + u;
    float4 acc4a[4], acc4b[4];
    if (l == 0) {
#pragma unroll
        for (int k = 0; k < 4; k++) acc4a[k] = xp[(size_t)k * 64];
    } else {
#pragma unroll
        for (int k = 0; k < 4; k++) acc4a[k] = bl;
    }
#pragma unroll
    for (int k = 0; k < 4; k++) acc4b[k] = bl;

    float* houtp = Hout + (size_t)b * T * 64 + u;
    const u4v* hs = (const u4v*)&hself[l][0];
    const u4v* wb = wihS + (size_t)(l > 0 ? l - 1 : 0) * 2048 + u;
    const int lb = (l > 0 ? l - 1 : 0);

    // pre-read h-quad registers (issued early, consumed next tick)
    u4v hq0 = {0,0,0,0}, hq1 = hq0, hq2 = hq0, hq3 = hq0;
    u4v hq4 = hq0, hq5 = hq0, hq6 = hq0, hq7 = hq0;

    __syncthreads();

#define FD(HP, WV, A) A = __builtin_amdgcn_fdot2(asH2(HP), asH2(WV), A, false)
#define FD4(HQ, WQ, A) { FD(HQ.x, (WQ).x, A); FD(HQ.y, (WQ).y, A); \
                         FD(HQ.z, (WQ).z, A); FD(HQ.w, (WQ).w, A); }

#define HQ_RELOAD() { hq0 = hs[0]; hq1 = hs[1]; hq2 = hs[2]; hq3 = hs[3]; \
                      hq4 = hs[4]; hq5 = hs[5]; hq6 = hs[6]; hq7 = hs[7]; }

    // one gate-column of one k-slice of the chunk-GEMM (wq read once / 4 ticks)
#define GEMMG2(G, KS, ACCSEL, ACC) {                                    \
    u4v wq = wb[((KS) >> 2) * 1024 + ((G) * 4 + ((KS) & 3)) * 64];      \
    FD4(hb0, wq, ACC[0].ACCSEL);                                        \
    FD4(hb1, wq, ACC[1].ACCSEL);                                        \
    FD4(hb2, wq, ACC[2].ACCSEL);                                        \
    FD4(hb3, wq, ACC[3].ACCSEL);                                        \
}
#define GEMMSLICE(H, KS, ACC) {                                         \
    u4v hb0 = hbase[((H) * 4 + 0) * 8 + (KS)];                          \
    u4v hb1 = hbase[((H) * 4 + 1) * 8 + (KS)];                          \
    u4v hb2 = hbase[((H) * 4 + 2) * 8 + (KS)];                          \
    u4v hb3 = hbase[((H) * 4 + 3) * 8 + (KS)];                          \
    GEMMG2(0, KS, x, ACC) GEMMG2(1, KS, y, ACC)                         \
    GEMMG2(2, KS, z, ACC) GEMMG2(3, KS, w, ACC)                         \
}

    // one LSTM tick: resident Whh x pre-read h-quads, 16 partial accums
    // (chains 8-deep, ILP 16), tree-combine, activations, h publish,
    // then immediately pre-read next tick's h-quads.
#define SCANTICK(XV, TAU, PUBR) {                                       \
    float4 xv_ = (XV);                                                  \
    float aI0=0.f,aF0=0.f,aG0=0.f,aO0=0.f;                              \
    float aI1=0.f,aF1=0.f,aG1=0.f,aO1=0.f;                              \
    float aI2=0.f,aF2=0.f,aG2=0.f,aO2=0.f;                              \
    float aI3=0.f,aF3=0.f,aG3=0.f,aO3=0.f;                              \
    FD4(hq0, whh[0],  aI0); FD4(hq0, whh[8],  aF0);                     \
    FD4(hq0, whh[16], aG0); FD4(hq0, whh[24], aO0);                     \
    FD4(hq1, whh[1],  aI1); FD4(hq1, whh[9],  aF1);                     \
    FD4(hq1, whh[17], aG1); FD4(hq1, whh[25], aO1);                     \
    FD4(hq2, whh[2],  aI2); FD4(hq2, whh[10], aF2);                     \
    FD4(hq2, whh[18], aG2); FD4(hq2, whh[26], aO2);                     \
    FD4(hq3, whh[3],  aI3); FD4(hq3, whh[11], aF3);                     \
    FD4(hq3, whh[19], aG3); FD4(hq3, whh[27], aO3);                     \
    FD4(hq4, whh[4],  aI0); FD4(hq4, whh[12], aF0);                     \
    FD4(hq4, whh[20], aG0); FD4(hq4, whh[28], aO0);                     \
    FD4(hq5, whh[5],  aI1); FD4(hq5, whh[13], aF1);                     \
    FD4(hq5, whh[21], aG1); FD4(hq5, whh[29], aO1);                     \
    FD4(hq6, whh[6],  aI2); FD4(hq6, whh[14], aF2);                     \
    FD4(hq6, whh[22], aG2); FD4(hq6, whh[30], aO2);                     \
    FD4(hq7, whh[7],  aI3); FD4(hq7, whh[15], aF3);                     \
    FD4(hq7, whh[23], aG3); FD4(hq7, whh[31], aO3);                     \
    float aI = ((aI0 + aI1) + (aI2 + aI3)) + xv_.x;                     \
    float aF = ((aF0 + aF1) + (aF2 + aF3)) + xv_.y;                     \
    float aG = ((aG0 + aG1) + (aG2 + aG3)) + xv_.z;                     \
    float aO = ((aO0 + aO1) + (aO2 + aO3)) + xv_.w;                     \
    cst = sigmoidf_(aF) * cst + sigmoidf_(aI) * tanhf_(aG);             \
    float hv = sigmoidf_(aO) * tanhf_(cst);                             \
    hself[l][u] = (_Float16)hv;                                         \
    if (l < 2) hpub[(PUBR) * 64 + u] = (_Float16)hv;                    \
    else       houtp[(size_t)(TAU) * 64] = hv;                          \
    HQ_RELOAD();                                                        \
}

    const int NC = T / RR;
    for (int e = 0; e < NC + 2; e++) {
        int m = e - l;
        if (m >= 0 && m < NC) {
            const int p = m & 1;
            const int base = m * RR;
            _Float16* hpub = &hchunk[l < 2 ? l : 0][p][0][0];
            if (m == 0) HQ_RELOAD();            // h(-1) = h0

            if (l == 0) {
#pragma unroll
                for (int r = 0; r < RR; r++) {
                    int tau = base + r;
                    float4 xv = acc4a[r & 3];
                    int tp = tau + 4; if (tp > T - 1) tp = T - 1;
                    acc4a[r & 3] = xp[(size_t)tp * 64];
                    SCANTICK(xv, tau, r)
                }
            } else {
                const u4v* hbase = (const u4v*)&hchunk[lb][p][0][0];
                // half-0 batch (preacts for ticks 0-3)
                acc4a[0] = bl; acc4a[1] = bl; acc4a[2] = bl; acc4a[3] = bl;
                GEMMSLICE(0, 0, acc4a) GEMMSLICE(0, 1, acc4a)
                GEMMSLICE(0, 2, acc4a) GEMMSLICE(0, 3, acc4a)
                GEMMSLICE(0, 4, acc4a) GEMMSLICE(0, 5, acc4a)
                GEMMSLICE(0, 6, acc4a) GEMMSLICE(0, 7, acc4a)
                // ticks 0-3, half-1 GEMM slices interleaved into the
                // h-read latency shadows (acc4b: no WAR with acc4a)
                acc4b[0] = bl; acc4b[1] = bl; acc4b[2] = bl; acc4b[3] = bl;
                SCANTICK(acc4a[0], base + 0, 0)
                GEMMSLICE(1, 0, acc4b) GEMMSLICE(1, 1, acc4b)
                SCANTICK(acc4a[1], base + 1, 1)
                GEMMSLICE(1, 2, acc4b) GEMMSLICE(1, 3, acc4b)
                SCANTICK(acc4a[2], base + 2, 2)
                GEMMSLICE(1, 4, acc4b) GEMMSLICE(1, 5, acc4b)
                SCANTICK(acc4a[3], base + 3, 3)
                GEMMSLICE(1, 6, acc4b) GEMMSLICE(1, 7, acc4b)
                // ticks 4-7
                SCANTICK(acc4b[0], base + 4, 4)
                SCANTICK(acc4b[1], base + 5, 5)
                SCANTICK(acc4b[2], base + 6, 6)
                SCANTICK(acc4b[3], base + 7, 7)
            }
        }
        LDS_BARRIER();   // publish hchunk writes; epoch parity flip
    }
#undef FD
#undef FD4
#undef HQ_RELOAD
#undef GEMMG2
#undef GEMMSLICE
#undef SCANTICK
}

// ---------------------------------------------------------------------------
// Hc[b, {max,mean,std(ddof=1)}, t] over hidden dim (64). One wave per (b,t).
// ---------------------------------------------------------------------------
__global__ __launch_bounds__(256) void stats_kernel(
    const float* __restrict__ H, float* __restrict__ Hc, int T)
{
    int wid = threadIdx.x >> 6, lane = threadIdx.x & 63;
    int bt = blockIdx.x * 4 + wid;
    int b = bt / T, t = bt - b * T;

    float x = H[(size_t)bt * 64 + lane];
    float mx = x, sm = x;
#pragma unroll
    for (int m = 32; m >= 1; m >>= 1) {
        mx = fmaxf(mx, __shfl_xor(mx, m));
        sm += __shfl_xor(sm, m);
    }
    float mean = sm * (1.0f / 64.0f);
    float d = x - mean;
    float ss = d * d;
#pragma unroll
    for (int m = 32; m >= 1; m >>= 1) ss += __shfl_xor(ss, m);
    float sd = sqrtf(ss * (1.0f / 63.0f));

    if (lane == 0) {
        float* o = Hc + (size_t)b * 3 * T;
        o[0 * T + t] = mx;
        o[1 * T + t] = mean;
        o[2 * T + t] = sd;
    }
}

// ---------------------------------------------------------------------------
// Middle conv/BN chain, single workgroup (1024 threads).
// ---------------------------------------------------------------------------
template <int CIN, int COUT, int MODE>
DEV void conv_bn_stage(const float* __restrict__ in, const float* __restrict__ w,
                       const float* __restrict__ bias, float* __restrict__ out,
                       float* __restrict__ gate, int T, int tid,
                       float* rs, float* rq, float* stm, float* sti)
{
    float lsum[COUT], lss[COUT];
#pragma unroll
    for (int oc = 0; oc < COUT; oc++) { lsum[oc] = 0.f; lss[oc] = 0.f; }

    for (int k = 0; k < 8; k++) {
        int p = tid + k * 1024;
        int b = p / T;
        int t = p - b * T;
        float acc[COUT];
#pragma unroll
        for (int oc = 0; oc < COUT; oc++) acc[oc] = bias[oc];
#pragma unroll
        for (int ic = 0; ic < CIN; ic++) {
            const float* row = in + ((size_t)b * CIN + ic) * T;
            float xv[11];
#pragma unroll
            for (int kk = 0; kk < 11; kk++) {
                int tt = t + kk - 5;
                xv[kk] = (tt >= 0 && tt < T) ? row[tt] : 0.f;
            }
#pragma unroll
            for (int oc = 0; oc < COUT; oc++) {
                const float* wr = w + ((size_t)oc * CIN + ic) * 11;
#pragma unroll
                for (int kk = 0; kk < 11; kk++) acc[oc] += xv[kk] * wr[kk];
            }
        }
#pragma unroll
        for (int oc = 0; oc < COUT; oc++) {
            out[((size_t)b * COUT + oc) * T + t] = acc[oc];
            lsum[oc] += acc[oc];
            lss[oc] += acc[oc] * acc[oc];
        }
    }
    __syncthreads();

    int lane = tid & 63, wid = tid >> 6;
#pragma unroll
    for (int oc = 0; oc < COUT; oc++) {
        float s = lsum[oc], qq = lss[oc];
#pragma unroll
        for (int m = 32; m >= 1; m >>= 1) {
            s += __shfl_xor(s, m);
            qq += __shfl_xor(qq, m);
        }
        if (lane == 0) { rs[wid] = s; rq[wid] = qq; }
        __syncthreads();
        if (tid == 0) {
            float S = 0.f, Q = 0.f;
            for (int i = 0; i < 16; i++) { S += rs[i]; Q += rq[i]; }
            float m_ = S / (float)(2 * T);
            float v = Q / (float)(2 * T) - m_ * m_;
            stm[oc] = m_;
            sti[oc] = rsqrtf(v + 1e-5f);
        }
        __syncthreads();
    }

    for (int k = 0; k < 8; k++) {
        int p = tid + k * 1024;
        int b = p / T;
        int t = p - b * T;
#pragma unroll
        for (int oc = 0; oc < COUT; oc++) {
            size_t idx = ((size_t)b * COUT + oc) * T + t;
            float v = (out[idx] - stm[oc]) * sti[oc];
            if (MODE == 0) out[idx] = fmaxf(v, 0.f);
            else           gate[p] = sigmoidf_(v);
        }
    }
    __syncthreads();
}

__global__ __launch_bounds__(1024) void middle_kernel(
    const float* __restrict__ Hc,
    const float* __restrict__ w1, const float* __restrict__ b1,
    const float* __restrict__ w2, const float* __restrict__ b2,
    const float* __restrict__ w3, const float* __restrict__ b3,
    const float* __restrict__ w4, const float* __restrict__ b4,
    float* __restrict__ bufA, float* __restrict__ bufB,
    float* __restrict__ gate, int T)
{
    __shared__ float rs[16], rq[16], stm[8], sti[8];
    int tid = threadIdx.x;
    conv_bn_stage<3, 3, 0>(Hc,   w1, b1, bufA, nullptr, T, tid, rs, rq, stm, sti);
    conv_bn_stage<3, 5, 0>(bufA, w2, b2, bufB, nullptr, T, tid, rs, rq, stm, sti);
    conv_bn_stage<5, 5, 0>(bufB, w3, b3, bufA, nullptr, T, tid, rs, rq, stm, sti);
    conv_bn_stage<5, 1, 1>(bufA, w4, b4, bufB, gate,    T, tid, rs, rq, stm, sti);
}

// ---------------------------------------------------------------------------
// Head: y = sigmoid(fc2(fc1(out2))). One wave per (b,t).
// ---------------------------------------------------------------------------
__global__ __launch_bounds__(256) void final_kernel(
    const float* __restrict__ out2, const float* __restrict__ fc1w,
    const float* __restrict__ fc1b, const float* __restrict__ fc2w,
    const float* __restrict__ fc2b, float* __restrict__ out, int T)
{
    int wid = threadIdx.x >> 6, lane = threadIdx.x & 63;
    int bt = blockIdx.x * 4 + wid;

    const float* o2 = out2 + (size_t)bt * 64;
    float acc = fc1b[lane];
    const float* wr = fc1w + (size_t)lane * 64;
#pragma unroll
    for (int k = 0; k < 64; k++) acc += o2[k] * wr[k];

    float p = acc * fc2w[lane];
#pragma unroll
    for (int m = 32; m >= 1; m >>= 1) p += __shfl_xor(p, m);

    if (lane == 0) out[bt] = sigmoidf_(p + fc2b[0]);
}

// ---------------------------------------------------------------------------
extern "C" void kernel_launch(void* const* d_in, const int* in_sizes, int n_in,
                              void* d_out, int out_size, void* d_ws, size_t ws_size,
                              hipStream_t stream)
{
    const float* data  = (const float*)d_in[0];
    const float* h01   = (const float*)d_in[1];
    const float* c01   = (const float*)d_in[2];
    const float* h02   = (const float*)d_in[3];
    const float* c02   = (const float*)d_in[4];
    const float* Wih0  = (const float*)d_in[5];
    const float* Wih12 = (const float*)d_in[6];
    const float* l1Whh = (const float*)d_in[7];
    const float* l1b   = (const float*)d_in[8];
    const float* l2Wih = (const float*)d_in[9];
    const float* l2Whh = (const float*)d_in[10];
    const float* l2b   = (const float*)d_in[11];
    const float* cw1 = (const float*)d_in[12]; const float* cb1 = (const float*)d_in[13];
    const float* cw2 = (const float*)d_in[14]; const float* cb2 = (const float*)d_in[15];
    const float* cw3 = (const float*)d_in[16]; const float* cb3 = (const float*)d_in[17];
    const float* cw4 = (const float*)d_in[18]; const float* cb4 = (const float*)d_in[19];
    const float* fc1w = (const float*)d_in[20]; const float* fc1b = (const float*)d_in[21];
    const float* fc2w = (const float*)d_in[22]; const float* fc2b = (const float*)d_in[23];
    float* out = (float*)d_out;

    const int T = in_sizes[0] / (2 * 40);   // 4096
    const int B = 2;

    float* ws   = (float*)d_ws;
    float* xg   = ws;                                // B*T*256
    float* seqA = xg   + (size_t)B * T * 256;        // B*T*64
    float* seqB = seqA + (size_t)B * T * 64;         // B*T*64
    float* Hc   = seqB + (size_t)B * T * 64;         // B*3*T
    float* bufA = Hc   + (size_t)B * 3 * T;          // B*5*T
    float* bufB = bufA + (size_t)B * 5 * T;          // B*5*T
    float* gate = bufB + (size_t)B * 5 * T;          // B*T
    unsigned* wP = (unsigned*)(gate + (size_t)B * T); // 10*8192 u32

    dim3 pg(B * (T / 16)), pb(256);

    pack_w<<<320, 256, 0, stream>>>(l1Whh, l2Whh, Wih12, l2Wih, wP);

    // ---- LSTM1: proj layer0 + chunked 3-layer scan ----
    proj_kernel<<<pg, pb, 0, stream>>>(data, Wih0, l1b, nullptr, xg, 40, T);
    scan3_kernel<<<2, 192, 0, stream>>>(xg, wP, wP + 6 * 8192, l1b, h01, c01, seqA, T);

    // ---- temporal-attention gate ----
    stats_kernel<<<(2 * T) / 4, 256, 0, stream>>>(seqA, Hc, T);
    middle_kernel<<<1, 1024, 0, stream>>>(Hc, cw1, cb1, cw2, cb2, cw3, cb3, cw4, cb4,
                                          bufA, bufB, gate, T);

    // ---- LSTM2: proj layer0 (gate folded) + chunked 3-layer scan ----
    proj_kernel<<<pg, pb, 0, stream>>>(seqA, l2Wih, l2b, gate, xg, 64, T);
    scan3_kernel<<<2, 192, 0, stream>>>(xg, wP + 3 * 8192, wP + 8 * 8192, l2b, h02, c02, seqB, T);

    // ---- head ----
    final_kernel<<<(2 * T) / 4, 256, 0, stream>>>(seqB, fc1w, fc1b, fc2w, fc2b, out, T);
}